// Round 21
// baseline (54.269 us; speedup 1.0000x reference)
//
#include <hip/hip_runtime.h>

#define NPRE 32768
#define NPOST 32768
#define RR 64
#define BATCH 512
#define KSPLIT 64
#define KCHUNK 512  // NPRE / KSPLIT

typedef float f32x4 __attribute__((ext_vector_type(4)));
typedef __bf16 bf16x8 __attribute__((ext_vector_type(8)));
typedef unsigned short u16;
typedef unsigned int u32;

static __device__ __forceinline__ float bf2f(u32 s) {
  return __builtin_bit_cast(float, s << 16);
}
// HW packed f32->bf16 (RNE), low16 = first arg (verified round 12).
static __device__ __forceinline__ u32 cvtpk(float lo, float hi) {
  u32 r;
  asm("v_cvt_pk_bf16_f32 %0, %1, %2" : "=v"(r) : "v"(lo), "v"(hi));
  return r;
}
static __device__ __forceinline__ bf16x8 pack8(f32x4 lo, f32x4 hi) {
  union { u32 w[4]; bf16x8 v; } u;
  u.w[0] = cvtpk(lo.x, lo.y);
  u.w[1] = cvtpk(lo.z, lo.w);
  u.w[2] = cvtpk(hi.x, hi.y);
  u.w[3] = cvtpk(hi.z, hi.w);
  return u.v;
}

// ---- prep: V f32 [NPRE][RR] -> Vt bf16 [RR][NPRE] (round-1 design + cvtpk) -
__global__ __launch_bounds__(256) void prep_v(const float* __restrict__ V,
                                              u16* __restrict__ Vt) {
  int k0 = blockIdx.x * 64 + (threadIdx.x >> 6) * 16;  // 16 k's per thread
  int r = threadIdx.x & 63;                            // lane -> r (coalesced)
  u32 pk[8];
#pragma unroll
  for (int j = 0; j < 8; ++j) {
    float a = V[(size_t)(k0 + 2 * j) * RR + r];
    float b = V[(size_t)(k0 + 2 * j + 1) * RR + r];
    pk[j] = cvtpk(a, b);
  }
  u16* dst = Vt + (size_t)r * NPRE + k0;  // 32 B contiguous per thread
  *reinterpret_cast<uint4*>(dst) = make_uint4(pk[0], pk[1], pk[2], pk[3]);
  *reinterpret_cast<uint4*>(dst + 8) = make_uint4(pk[4], pk[5], pk[6], pk[7]);
}

// ---- GEMM1 v3: Vt vector B-loads — 6 VMEM/iter (was 34) -------------------
// Theory: k1 was VMEM-ISSUE-bound (32 scalar V-loads/iter, 64B unique data
// each, 4x broadcast across g-groups). Vt[r][k] bf16 makes each B-fragment
// one 16-B bf16x8 load: per iter = 2 A-loads + 4 B-loads + 4 MFMA.
__global__ __launch_bounds__(256, 4) void k1(const float* __restrict__ S,
                                             const u16* __restrict__ Vt,
                                             u16* __restrict__ zp) {
  int bid = blockIdx.x;
  int eff = (bid & 7) * 64 + (bid >> 3);  // bijective XCD swizzle (512 % 8 == 0)
  int grp = eff & 7;
  int kc = eff >> 3;                       // 0..63, XCD-contiguous
  int lane = threadIdx.x & 63;
  int w = threadIdx.x >> 6;
  int mt = grp * 4 + w;                    // 0..31
  int l15 = lane & 15, g = lane >> 4;
  const float* A = S + (size_t)(mt * 16 + l15) * NPRE + kc * KCHUNK + g * 8;
  // B-fragment row = tt*16 + l15 (r), col = kc*KCHUNK + ks*32 + g*8 (k)
  const u16* B0 = Vt + (size_t)(0 * 16 + l15) * NPRE + kc * KCHUNK + g * 8;
  const u16* B1 = B0 + (size_t)16 * NPRE;
  const u16* B2 = B0 + (size_t)32 * NPRE;
  const u16* B3 = B0 + (size_t)48 * NPRE;
  f32x4 acc[4] = {};
#pragma unroll 4
  for (int ks = 0; ks < KCHUNK / 32; ++ks) {
    f32x4 a0 = *reinterpret_cast<const f32x4*>(A + ks * 32);
    f32x4 a1 = *reinterpret_cast<const f32x4*>(A + ks * 32 + 4);
    bf16x8 af = pack8(a0, a1);
    bf16x8 b0 = *reinterpret_cast<const bf16x8*>(B0 + ks * 32);
    bf16x8 b1 = *reinterpret_cast<const bf16x8*>(B1 + ks * 32);
    bf16x8 b2 = *reinterpret_cast<const bf16x8*>(B2 + ks * 32);
    bf16x8 b3 = *reinterpret_cast<const bf16x8*>(B3 + ks * 32);
    acc[0] = __builtin_amdgcn_mfma_f32_16x16x32_bf16(af, b0, acc[0], 0, 0, 0);
    acc[1] = __builtin_amdgcn_mfma_f32_16x16x32_bf16(af, b1, acc[1], 0, 0, 0);
    acc[2] = __builtin_amdgcn_mfma_f32_16x16x32_bf16(af, b2, acc[2], 0, 0, 0);
    acc[3] = __builtin_amdgcn_mfma_f32_16x16x32_bf16(af, b3, acc[3], 0, 0, 0);
  }
  u16* out = zp + ((size_t)kc * BATCH + mt * 16) * RR;
#pragma unroll
  for (int tt = 0; tt < 4; ++tt)
#pragma unroll
    for (int q = 0; q < 4; ++q)
      out[(g * 4 + q) * RR + tt * 16 + l15] = (u16)cvtpk(acc[tt][q], acc[tt][q]);
}

// ---- reduce (frozen): 64 partials, 4 tg x 16 each -------------------------
__global__ __launch_bounds__(1024) void k_red(const u16* __restrict__ zp,
                                              u16* __restrict__ zb) {
  __shared__ float pl[4][256], ph[4][256];
  int il = threadIdx.x & 255;
  int tg = threadIdx.x >> 8;
  int i2 = blockIdx.x * 256 + il;  // pair index, outputs {2*i2, 2*i2+1}
  const u32* p = reinterpret_cast<const u32*>(zp) +
                 (size_t)(tg * 16) * (BATCH * RR / 2) + i2;
  float sl = 0.f, sh = 0.f;
#pragma unroll
  for (int j = 0; j < 16; j += 4) {
    u32 w0 = p[(size_t)(j + 0) * (BATCH * RR / 2)];
    u32 w1 = p[(size_t)(j + 1) * (BATCH * RR / 2)];
    u32 w2 = p[(size_t)(j + 2) * (BATCH * RR / 2)];
    u32 w3 = p[(size_t)(j + 3) * (BATCH * RR / 2)];
    sl += (bf2f(w0 & 0xffffu) + bf2f(w1 & 0xffffu)) +
          (bf2f(w2 & 0xffffu) + bf2f(w3 & 0xffffu));
    sh += (bf2f(w0 >> 16) + bf2f(w1 >> 16)) + (bf2f(w2 >> 16) + bf2f(w3 >> 16));
  }
  pl[tg][il] = sl;
  ph[tg][il] = sh;
  __syncthreads();
  if (tg == 0) {
    float lo = (pl[0][il] + pl[1][il]) + (pl[2][il] + pl[3][il]);
    float hi = (ph[0][il] + ph[1][il]) + (ph[2][il] + ph[3][il]);
    reinterpret_cast<u32*>(zb)[i2] = cvtpk(lo, hi);
  }
}

// ---- GEMM2 v13 (frozen): full-column blocks + depth-4 zb prefetch ring ----
__global__ __launch_bounds__(256) void k2(const u16* __restrict__ zv,
                                          const float* __restrict__ U,
                                          float* __restrict__ y) {
  int bid = blockIdx.x;
  int eff = (bid & 7) * 32 + (bid >> 3);  // bijective (256 % 8 == 0)
  int n0 = eff * 128;                     // XCD-contiguous 4096-wide n ranges
  int t = threadIdx.x;
  int lane = t & 63;
  int w = t >> 6;                         // 0..3
  int l15 = lane & 15, g = lane >> 4;

  bf16x8 uA[2], uB[2];
#pragma unroll
  for (int j = 0; j < 2; ++j) {
    int row = (w + 4 * j) * 16 + l15;
    const float* Up = U + (size_t)(n0 + row) * RR + g * 8;
    f32x4 a = *reinterpret_cast<const f32x4*>(Up);
    f32x4 b = *reinterpret_cast<const f32x4*>(Up + 4);
    f32x4 c = *reinterpret_cast<const f32x4*>(Up + 32);
    f32x4 d = *reinterpret_cast<const f32x4*>(Up + 36);
    uA[j] = pack8(a, b);   // k 0..31 slice
    uB[j] = pack8(c, d);   // k 32..63 slice
  }

  const u16* Ab = zv + (size_t)l15 * RR + g * 8;  // b-row = it*16 + l15
  bf16x8 za[4], zc[4];
#pragma unroll
  for (int p = 0; p < 4; ++p) {
    za[p] = *reinterpret_cast<const bf16x8*>(Ab + (size_t)p * 16 * RR);
    zc[p] = *reinterpret_cast<const bf16x8*>(Ab + (size_t)p * 16 * RR + 32);
  }
#pragma unroll
  for (int it = 0; it < 32; ++it) {
    int cur = it & 3;  // compile-time within unrolled body (rule #20)
    f32x4 acc0 = {}, acc1 = {};
    acc0 = __builtin_amdgcn_mfma_f32_16x16x32_bf16(uA[0], za[cur], acc0, 0, 0, 0);
    acc0 = __builtin_amdgcn_mfma_f32_16x16x32_bf16(uB[0], zc[cur], acc0, 0, 0, 0);
    acc1 = __builtin_amdgcn_mfma_f32_16x16x32_bf16(uA[1], za[cur], acc1, 0, 0, 0);
    acc1 = __builtin_amdgcn_mfma_f32_16x16x32_bf16(uB[1], zc[cur], acc1, 0, 0, 0);
    if (it < 28) {  // refill ring slot BEFORE stores (loads precede stores)
      const u16* An = Ab + (size_t)(it + 4) * 16 * RR;
      za[cur] = *reinterpret_cast<const bf16x8*>(An);
      zc[cur] = *reinterpret_cast<const bf16x8*>(An + 32);
    }
    float* yb = y + (size_t)(it * 16 + l15) * NPOST + n0;
    *reinterpret_cast<f32x4*>(yb + w * 16 + g * 4) = acc0;
    *reinterpret_cast<f32x4*>(yb + (w + 4) * 16 + g * 4) = acc1;
  }
}

extern "C" void kernel_launch(void* const* d_in, const int* in_sizes, int n_in,
                              void* d_out, int out_size, void* d_ws, size_t ws_size,
                              hipStream_t stream) {
  const float* spikes = (const float*)d_in[0];
  const float* U = (const float*)d_in[1];
  const float* V = (const float*)d_in[2];
  // d_in[3..5]: CSR mask — dead in the reference, unused.
  float* y = (float*)d_out;
  char* ws = (char*)d_ws;
  u16* Vt = (u16*)ws;                    // 4 MiB  [RR][NPRE] bf16
  u16* zp = (u16*)(ws + (4u << 20));     // 4 MiB  [KSPLIT=64][BATCH][RR] bf16
  u16* zb = (u16*)(ws + (8u << 20));     // 64 KiB [BATCH][RR] bf16

  prep_v<<<NPRE / 64, 256, 0, stream>>>(V, Vt);
  k1<<<512, 256, 0, stream>>>(spikes, Vt, zp);
  k_red<<<64, 1024, 0, stream>>>(zp, zb);
  k2<<<256, 256, 0, stream>>>(zb, U, y);
}

// Round 22
// 43.508 us; speedup vs baseline: 1.2473x; 1.2473x over previous
//
#include <hip/hip_runtime.h>

#define NPRE 32768
#define NPOST 32768
#define RR 64
#define BATCH 512
#define KSPLIT 64
#define KCHUNK 512  // NPRE / KSPLIT

typedef float f32x4 __attribute__((ext_vector_type(4)));
typedef __bf16 bf16x8 __attribute__((ext_vector_type(8)));
typedef unsigned short u16;
typedef unsigned int u32;

static __device__ __forceinline__ float bf2f(u32 s) {
  return __builtin_bit_cast(float, s << 16);
}
// HW packed f32->bf16 (RNE), low16 = first arg (verified round 12).
static __device__ __forceinline__ u32 cvtpk(float lo, float hi) {
  u32 r;
  asm("v_cvt_pk_bf16_f32 %0, %1, %2" : "=v"(r) : "v"(lo), "v"(hi));
  return r;
}
static __device__ __forceinline__ bf16x8 pack8(f32x4 lo, f32x4 hi) {
  union { u32 w[4]; bf16x8 v; } u;
  u.w[0] = cvtpk(lo.x, lo.y);
  u.w[1] = cvtpk(lo.z, lo.w);
  u.w[2] = cvtpk(hi.x, hi.y);
  u.w[3] = cvtpk(hi.z, hi.w);
  return u.v;
}

// ---- GEMM1 (r20 form, reverted): zp[kc][b][r] = S[b][kslice] @ V ----------
__global__ __launch_bounds__(256, 4) void k1(const float* __restrict__ S,
                                             const float* __restrict__ V,
                                             u16* __restrict__ zp) {
  int bid = blockIdx.x;
  int eff = (bid & 7) * 64 + (bid >> 3);  // bijective XCD swizzle (512 % 8 == 0)
  int grp = eff & 7;
  int kc = eff >> 3;                       // 0..63, XCD-contiguous
  int lane = threadIdx.x & 63;
  int w = threadIdx.x >> 6;
  int mt = grp * 4 + w;                    // 0..31
  int l15 = lane & 15, g = lane >> 4;
  const float* A = S + (size_t)(mt * 16 + l15) * NPRE + kc * KCHUNK + g * 8;
  const float* Vb = V + (size_t)(kc * KCHUNK + g * 8) * RR + l15;
  f32x4 acc[4] = {};
#pragma unroll 2
  for (int ks = 0; ks < KCHUNK / 32; ++ks) {
    f32x4 a0 = *reinterpret_cast<const f32x4*>(A + ks * 32);
    f32x4 a1 = *reinterpret_cast<const f32x4*>(A + ks * 32 + 4);
    bf16x8 af = pack8(a0, a1);
    const float* Vk = Vb + (size_t)ks * 32 * RR;
    bf16x8 bfr[4];
#pragma unroll
    for (int tt = 0; tt < 4; ++tt) {
      f32x4 lo, hi;
      lo.x = Vk[0 * RR + tt * 16]; lo.y = Vk[1 * RR + tt * 16];
      lo.z = Vk[2 * RR + tt * 16]; lo.w = Vk[3 * RR + tt * 16];
      hi.x = Vk[4 * RR + tt * 16]; hi.y = Vk[5 * RR + tt * 16];
      hi.z = Vk[6 * RR + tt * 16]; hi.w = Vk[7 * RR + tt * 16];
      bfr[tt] = pack8(lo, hi);
    }
    acc[0] = __builtin_amdgcn_mfma_f32_16x16x32_bf16(af, bfr[0], acc[0], 0, 0, 0);
    acc[1] = __builtin_amdgcn_mfma_f32_16x16x32_bf16(af, bfr[1], acc[1], 0, 0, 0);
    acc[2] = __builtin_amdgcn_mfma_f32_16x16x32_bf16(af, bfr[2], acc[2], 0, 0, 0);
    acc[3] = __builtin_amdgcn_mfma_f32_16x16x32_bf16(af, bfr[3], acc[3], 0, 0, 0);
  }
  u16* out = zp + ((size_t)kc * BATCH + mt * 16) * RR;
#pragma unroll
  for (int tt = 0; tt < 4; ++tt)
#pragma unroll
    for (int q = 0; q < 4; ++q)
      out[(g * 4 + q) * RR + tt * 16 + l15] = (u16)cvtpk(acc[tt][q], acc[tt][q]);
}

// ---- reduce (frozen): 64 partials, 4 tg x 16 each -------------------------
__global__ __launch_bounds__(1024) void k_red(const u16* __restrict__ zp,
                                              u16* __restrict__ zb) {
  __shared__ float pl[4][256], ph[4][256];
  int il = threadIdx.x & 255;
  int tg = threadIdx.x >> 8;
  int i2 = blockIdx.x * 256 + il;  // pair index, outputs {2*i2, 2*i2+1}
  const u32* p = reinterpret_cast<const u32*>(zp) +
                 (size_t)(tg * 16) * (BATCH * RR / 2) + i2;
  float sl = 0.f, sh = 0.f;
#pragma unroll
  for (int j = 0; j < 16; j += 4) {
    u32 w0 = p[(size_t)(j + 0) * (BATCH * RR / 2)];
    u32 w1 = p[(size_t)(j + 1) * (BATCH * RR / 2)];
    u32 w2 = p[(size_t)(j + 2) * (BATCH * RR / 2)];
    u32 w3 = p[(size_t)(j + 3) * (BATCH * RR / 2)];
    sl += (bf2f(w0 & 0xffffu) + bf2f(w1 & 0xffffu)) +
          (bf2f(w2 & 0xffffu) + bf2f(w3 & 0xffffu));
    sh += (bf2f(w0 >> 16) + bf2f(w1 >> 16)) + (bf2f(w2 >> 16) + bf2f(w3 >> 16));
  }
  pl[tg][il] = sl;
  ph[tg][il] = sh;
  __syncthreads();
  if (tg == 0) {
    float lo = (pl[0][il] + pl[1][il]) + (pl[2][il] + pl[3][il]);
    float hi = (ph[0][il] + ph[1][il]) + (ph[2][il] + ph[3][il]);
    reinterpret_cast<u32*>(zb)[i2] = cvtpk(lo, hi);
  }
}

// ---- GEMM2 v14: v13 structure at 2 waves/SIMD (occupancy A/B) -------------
// 512 blocks x 256 thr; block = n-tile 128 x b-half 256 (16 its). Same
// barrier-free long-stream + reg-U + depth-4 ring as v13; only concurrency
// doubles (2 blocks/CU). Theory: v13's residual ~12us is latency exposure
// at 1 wave/SIMD — any zb-refill stall idles the SIMD entirely.
__global__ __launch_bounds__(256) void k2(const u16* __restrict__ zv,
                                          const float* __restrict__ U,
                                          float* __restrict__ y) {
  int bid = blockIdx.x;
  int eff = (bid & 7) * 64 + (bid >> 3);  // bijective (512 % 8 == 0)
  int n0 = (eff >> 1) * 128;              // XCD-contiguous n ranges
  int bb = (eff & 1) * 256;               // batch half
  int t = threadIdx.x;
  int lane = t & 63;
  int w = t >> 6;                         // 0..3
  int l15 = lane & 15, g = lane >> 4;

  // U fragments -> registers, once. Wave w owns taus {w, w+4} (rows 0..127).
  bf16x8 uA[2], uB[2];
#pragma unroll
  for (int j = 0; j < 2; ++j) {
    int row = (w + 4 * j) * 16 + l15;
    const float* Up = U + (size_t)(n0 + row) * RR + g * 8;
    f32x4 a = *reinterpret_cast<const f32x4*>(Up);
    f32x4 b = *reinterpret_cast<const f32x4*>(Up + 4);
    f32x4 c = *reinterpret_cast<const f32x4*>(Up + 32);
    f32x4 d = *reinterpret_cast<const f32x4*>(Up + 36);
    uA[j] = pack8(a, b);   // k 0..31 slice
    uB[j] = pack8(c, d);   // k 32..63 slice
  }

  const u16* Ab = zv + (size_t)(bb + l15) * RR + g * 8;  // b = bb + it*16 + l15
  bf16x8 za[4], zc[4];
#pragma unroll
  for (int p = 0; p < 4; ++p) {
    za[p] = *reinterpret_cast<const bf16x8*>(Ab + (size_t)p * 16 * RR);
    zc[p] = *reinterpret_cast<const bf16x8*>(Ab + (size_t)p * 16 * RR + 32);
  }
#pragma unroll
  for (int it = 0; it < 16; ++it) {
    int cur = it & 3;  // compile-time within unrolled body (rule #20)
    f32x4 acc0 = {}, acc1 = {};
    acc0 = __builtin_amdgcn_mfma_f32_16x16x32_bf16(uA[0], za[cur], acc0, 0, 0, 0);
    acc0 = __builtin_amdgcn_mfma_f32_16x16x32_bf16(uB[0], zc[cur], acc0, 0, 0, 0);
    acc1 = __builtin_amdgcn_mfma_f32_16x16x32_bf16(uA[1], za[cur], acc1, 0, 0, 0);
    acc1 = __builtin_amdgcn_mfma_f32_16x16x32_bf16(uB[1], zc[cur], acc1, 0, 0, 0);
    if (it < 12) {  // refill ring slot BEFORE stores (loads precede stores)
      const u16* An = Ab + (size_t)(it + 4) * 16 * RR;
      za[cur] = *reinterpret_cast<const bf16x8*>(An);
      zc[cur] = *reinterpret_cast<const bf16x8*>(An + 32);
    }
    // D: col=l15 <-> b, row=g*4+q <-> n; lane stores 4 consecutive n (16B)
    float* yb = y + (size_t)(bb + it * 16 + l15) * NPOST + n0;
    *reinterpret_cast<f32x4*>(yb + w * 16 + g * 4) = acc0;
    *reinterpret_cast<f32x4*>(yb + (w + 4) * 16 + g * 4) = acc1;
  }
}

extern "C" void kernel_launch(void* const* d_in, const int* in_sizes, int n_in,
                              void* d_out, int out_size, void* d_ws, size_t ws_size,
                              hipStream_t stream) {
  const float* spikes = (const float*)d_in[0];
  const float* U = (const float*)d_in[1];
  const float* V = (const float*)d_in[2];
  // d_in[3..5]: CSR mask — dead in the reference, unused.
  float* y = (float*)d_out;
  char* ws = (char*)d_ws;
  u16* zp = (u16*)ws;                    // 4 MiB  [KSPLIT=64][BATCH][RR] bf16
  u16* zb = (u16*)(ws + (4u << 20));     // 64 KiB [BATCH][RR] bf16

  k1<<<512, 256, 0, stream>>>(spikes, V, zp);
  k_red<<<64, 1024, 0, stream>>>(zp, zb);
  k2<<<512, 256, 0, stream>>>(zb, U, y);
}

// Round 24
// 42.879 us; speedup vs baseline: 1.2656x; 1.0147x over previous
//
#include <hip/hip_runtime.h>

#define NPRE 32768
#define NPOST 32768
#define RR 64
#define BATCH 512
#define KSPLIT 64
#define KCHUNK 512  // NPRE / KSPLIT

typedef float f32x4 __attribute__((ext_vector_type(4)));
typedef __bf16 bf16x8 __attribute__((ext_vector_type(8)));
typedef unsigned short u16;
typedef unsigned int u32;

static __device__ __forceinline__ float bf2f(u32 s) {
  return __builtin_bit_cast(float, s << 16);
}
// HW packed f32->bf16 (RNE), low16 = first arg (verified round 12).
static __device__ __forceinline__ u32 cvtpk(float lo, float hi) {
  u32 r;
  asm("v_cvt_pk_bf16_f32 %0, %1, %2" : "=v"(r) : "v"(lo), "v"(hi));
  return r;
}
static __device__ __forceinline__ bf16x8 pack8(f32x4 lo, f32x4 hi) {
  union { u32 w[4]; bf16x8 v; } u;
  u.w[0] = cvtpk(lo.x, lo.y);
  u.w[1] = cvtpk(lo.z, lo.w);
  u.w[2] = cvtpk(hi.x, hi.y);
  u.w[3] = cvtpk(hi.z, hi.w);
  return u.v;
}

// ---- GEMM1 (r20 proven form): zp[kc][b][r] = S[b][kslice] @ V --------------
__global__ __launch_bounds__(256, 4) void k1(const float* __restrict__ S,
                                             const float* __restrict__ V,
                                             u16* __restrict__ zp) {
  int bid = blockIdx.x;
  int eff = (bid & 7) * 64 + (bid >> 3);  // bijective XCD swizzle (512 % 8 == 0)
  int grp = eff & 7;
  int kc = eff >> 3;                       // 0..63, XCD-contiguous
  int lane = threadIdx.x & 63;
  int w = threadIdx.x >> 6;
  int mt = grp * 4 + w;                    // 0..31
  int l15 = lane & 15, g = lane >> 4;
  const float* A = S + (size_t)(mt * 16 + l15) * NPRE + kc * KCHUNK + g * 8;
  const float* Vb = V + (size_t)(kc * KCHUNK + g * 8) * RR + l15;
  f32x4 acc[4] = {};
#pragma unroll 2
  for (int ks = 0; ks < KCHUNK / 32; ++ks) {
    f32x4 a0 = *reinterpret_cast<const f32x4*>(A + ks * 32);
    f32x4 a1 = *reinterpret_cast<const f32x4*>(A + ks * 32 + 4);
    bf16x8 af = pack8(a0, a1);
    const float* Vk = Vb + (size_t)ks * 32 * RR;
    bf16x8 bfr[4];
#pragma unroll
    for (int tt = 0; tt < 4; ++tt) {
      f32x4 lo, hi;
      lo.x = Vk[0 * RR + tt * 16]; lo.y = Vk[1 * RR + tt * 16];
      lo.z = Vk[2 * RR + tt * 16]; lo.w = Vk[3 * RR + tt * 16];
      hi.x = Vk[4 * RR + tt * 16]; hi.y = Vk[5 * RR + tt * 16];
      hi.z = Vk[6 * RR + tt * 16]; hi.w = Vk[7 * RR + tt * 16];
      bfr[tt] = pack8(lo, hi);
    }
    acc[0] = __builtin_amdgcn_mfma_f32_16x16x32_bf16(af, bfr[0], acc[0], 0, 0, 0);
    acc[1] = __builtin_amdgcn_mfma_f32_16x16x32_bf16(af, bfr[1], acc[1], 0, 0, 0);
    acc[2] = __builtin_amdgcn_mfma_f32_16x16x32_bf16(af, bfr[2], acc[2], 0, 0, 0);
    acc[3] = __builtin_amdgcn_mfma_f32_16x16x32_bf16(af, bfr[3], acc[3], 0, 0, 0);
  }
  u16* out = zp + ((size_t)kc * BATCH + mt * 16) * RR;
#pragma unroll
  for (int tt = 0; tt < 4; ++tt)
#pragma unroll
    for (int q = 0; q < 4; ++q)
      out[(g * 4 + q) * RR + tt * 16 + l15] = (u16)cvtpk(acc[tt][q], acc[tt][q]);
}

// ---- reduce (frozen): 64 partials, 4 tg x 16 each -------------------------
__global__ __launch_bounds__(1024) void k_red(const u16* __restrict__ zp,
                                              u16* __restrict__ zb) {
  __shared__ float pl[4][256], ph[4][256];
  int il = threadIdx.x & 255;
  int tg = threadIdx.x >> 8;
  int i2 = blockIdx.x * 256 + il;  // pair index, outputs {2*i2, 2*i2+1}
  const u32* p = reinterpret_cast<const u32*>(zp) +
                 (size_t)(tg * 16) * (BATCH * RR / 2) + i2;
  float sl = 0.f, sh = 0.f;
#pragma unroll
  for (int j = 0; j < 16; j += 4) {
    u32 w0 = p[(size_t)(j + 0) * (BATCH * RR / 2)];
    u32 w1 = p[(size_t)(j + 1) * (BATCH * RR / 2)];
    u32 w2 = p[(size_t)(j + 2) * (BATCH * RR / 2)];
    u32 w3 = p[(size_t)(j + 3) * (BATCH * RR / 2)];
    sl += (bf2f(w0 & 0xffffu) + bf2f(w1 & 0xffffu)) +
          (bf2f(w2 & 0xffffu) + bf2f(w3 & 0xffffu));
    sh += (bf2f(w0 >> 16) + bf2f(w1 >> 16)) + (bf2f(w2 >> 16) + bf2f(w3 >> 16));
  }
  pl[tg][il] = sl;
  ph[tg][il] = sh;
  __syncthreads();
  if (tg == 0) {
    float lo = (pl[0][il] + pl[1][il]) + (pl[2][il] + pl[3][il]);
    float hi = (ph[0][il] + ph[1][il]) + (ph[2][il] + ph[3][il]);
    reinterpret_cast<u32*>(zb)[i2] = cvtpk(lo, hi);
  }
}

// ---- GEMM2 v13 (r20 proven best): full-column + depth-4 ring --------------
__global__ __launch_bounds__(256) void k2(const u16* __restrict__ zv,
                                          const float* __restrict__ U,
                                          float* __restrict__ y) {
  int bid = blockIdx.x;
  int eff = (bid & 7) * 32 + (bid >> 3);  // bijective (256 % 8 == 0)
  int n0 = eff * 128;                     // XCD-contiguous 4096-wide n ranges
  int t = threadIdx.x;
  int lane = t & 63;
  int w = t >> 6;                         // 0..3
  int l15 = lane & 15, g = lane >> 4;

  bf16x8 uA[2], uB[2];
#pragma unroll
  for (int j = 0; j < 2; ++j) {
    int row = (w + 4 * j) * 16 + l15;
    const float* Up = U + (size_t)(n0 + row) * RR + g * 8;
    f32x4 a = *reinterpret_cast<const f32x4*>(Up);
    f32x4 b = *reinterpret_cast<const f32x4*>(Up + 4);
    f32x4 c = *reinterpret_cast<const f32x4*>(Up + 32);
    f32x4 d = *reinterpret_cast<const f32x4*>(Up + 36);
    uA[j] = pack8(a, b);   // k 0..31 slice
    uB[j] = pack8(c, d);   // k 32..63 slice
  }

  const u16* Ab = zv + (size_t)l15 * RR + g * 8;  // b-row = it*16 + l15
  bf16x8 za[4], zc[4];
#pragma unroll
  for (int p = 0; p < 4; ++p) {
    za[p] = *reinterpret_cast<const bf16x8*>(Ab + (size_t)p * 16 * RR);
    zc[p] = *reinterpret_cast<const bf16x8*>(Ab + (size_t)p * 16 * RR + 32);
  }
#pragma unroll
  for (int it = 0; it < 32; ++it) {
    int cur = it & 3;  // compile-time within unrolled body (rule #20)
    f32x4 acc0 = {}, acc1 = {};
    acc0 = __builtin_amdgcn_mfma_f32_16x16x32_bf16(uA[0], za[cur], acc0, 0, 0, 0);
    acc0 = __builtin_amdgcn_mfma_f32_16x16x32_bf16(uB[0], zc[cur], acc0, 0, 0, 0);
    acc1 = __builtin_amdgcn_mfma_f32_16x16x32_bf16(uA[1], za[cur], acc1, 0, 0, 0);
    acc1 = __builtin_amdgcn_mfma_f32_16x16x32_bf16(uB[1], zc[cur], acc1, 0, 0, 0);
    if (it < 28) {  // refill ring slot BEFORE stores (loads precede stores)
      const u16* An = Ab + (size_t)(it + 4) * 16 * RR;
      za[cur] = *reinterpret_cast<const bf16x8*>(An);
      zc[cur] = *reinterpret_cast<const bf16x8*>(An + 32);
    }
    float* yb = y + (size_t)(it * 16 + l15) * NPOST + n0;
    *reinterpret_cast<f32x4*>(yb + w * 16 + g * 4) = acc0;
    *reinterpret_cast<f32x4*>(yb + (w + 4) * 16 + g * 4) = acc1;
  }
}

extern "C" void kernel_launch(void* const* d_in, const int* in_sizes, int n_in,
                              void* d_out, int out_size, void* d_ws, size_t ws_size,
                              hipStream_t stream) {
  const float* spikes = (const float*)d_in[0];
  const float* U = (const float*)d_in[1];
  const float* V = (const float*)d_in[2];
  // d_in[3..5]: CSR mask — dead in the reference, unused.
  float* y = (float*)d_out;
  char* ws = (char*)d_ws;
  u16* zp = (u16*)ws;                    // 4 MiB  [KSPLIT=64][BATCH][RR] bf16
  u16* zb = (u16*)(ws + (4u << 20));     // 64 KiB [BATCH][RR] bf16

  k1<<<512, 256, 0, stream>>>(spikes, V, zp);
  k_red<<<64, 1024, 0, stream>>>(zp, zb);
  k2<<<256, 256, 0, stream>>>(zb, U, y);
}